// Round 10
// baseline (1143.724 us; speedup 1.0000x reference)
//
#include <hip/hip_runtime.h>
#include <hip/hip_bf16.h>

// GAT layer, N=8192, DIN=256, DOUT=128.
// R17: DIAGNOSTIC ROUND. Real pipeline = R16 unchanged (best, 426us).
// Appended: three probe dispatches replicating the R16 gat_attn body with
// REPS=8 internal repeats so they exceed the ~160us workspace-poison fills
// and land in the rocprof top-5 with full counters. MODE 0 = full kernel;
// MODE 1 = softmax stubbed (af=ones, loads kept live via asm, per rule #17);
// MODE 2 = B-read+MFMA f-loop stubbed (af kept live per-VGPR). Probes write
// to scratch at ws+120MB; they run AFTER the real pipeline so real outputs
// are untouched. This round's dur_us is intentionally ~1.9ms; the info is
// the decomposition of the ~85us attn stall that 5 rounds of single-theory
// edits failed to find (occupancy/VMEM/regs/I$/nt all ~null).

#define NN 8192
#define DIN 256
#define DOUT 128
#define LOG2E 1.4426950408889634f

typedef __attribute__((ext_vector_type(8))) short short8;   // 8 bf16 = 4 VGPRs (MFMA A/B frag)
typedef __attribute__((ext_vector_type(4))) float floatx4;  // MFMA C/D frag

// ---------------- kernel 0: W [256][128] fp32 -> WT [128][256] bf16 ----------------
__global__ void prep_wt(const float* __restrict__ W, __hip_bfloat16* __restrict__ WT) {
    int e = blockIdx.x * blockDim.x + threadIdx.x;
    if (e < DIN * DOUT) {
        int k = e >> 7;
        int d = e & 127;
        WT[d * DIN + k] = __float2bfloat16(W[e]);
    }
}

// ---------------- kernel 1: h = x@W + bW (MFMA), fused s_src/s_dst ----------------
__global__ __launch_bounds__(256, 4) void gat_h(
    const float* __restrict__ x, const __hip_bfloat16* __restrict__ WT,
    const float* __restrict__ bW, const float* __restrict__ a1, const float* __restrict__ a2,
    __hip_bfloat16* __restrict__ hbB, float* __restrict__ s_src, float* __restrict__ s_dst) {
    int tid = threadIdx.x;
    int w = tid >> 6, lane = tid & 63;
    int lm = lane & 15, lq = lane >> 4;
    int i0 = blockIdx.x * 32;
    int r0 = (w >> 1) * 16;
    int c0 = (w & 1) * 64;

    __shared__ float s1s[32], s2s[32];
    if (tid < 32) { s1s[tid] = 0.f; s2s[tid] = 0.f; }
    __syncthreads();

    floatx4 acc[4] = {};
#pragma unroll
    for (int kk = 0; kk < DIN; kk += 32) {
        const float4* xp = (const float4*)&x[(size_t)(i0 + r0 + lm) * DIN + kk + lq * 8];
        float4 xa = xp[0], xb = xp[1];
        union { short8 v; __hip_bfloat16 h[8]; } af;
        af.h[0] = __float2bfloat16(xa.x); af.h[1] = __float2bfloat16(xa.y);
        af.h[2] = __float2bfloat16(xa.z); af.h[3] = __float2bfloat16(xa.w);
        af.h[4] = __float2bfloat16(xb.x); af.h[5] = __float2bfloat16(xb.y);
        af.h[6] = __float2bfloat16(xb.z); af.h[7] = __float2bfloat16(xb.w);
#pragma unroll
        for (int t = 0; t < 4; t++) {
            int d = c0 + 16 * t + lm;
            short8 bf = *(const short8*)&WT[(size_t)d * DIN + kk + lq * 8];
            acc[t] = __builtin_amdgcn_mfma_f32_16x16x32_bf16(af.v, bf, acc[t], 0, 0, 0);
        }
    }
    float s1[4] = {0.f, 0.f, 0.f, 0.f}, s2[4] = {0.f, 0.f, 0.f, 0.f};
#pragma unroll
    for (int t = 0; t < 4; t++) {
        int d = c0 + 16 * t + lm;
        int f = (c0 >> 4) + t;
        float A1 = a1[d], A2 = a2[d], B = bW[d];
#pragma unroll
        for (int r = 0; r < 4; r++) {
            int k = r0 + lq * 4 + r;
            float h = acc[t][r] + B;
            hbB[(size_t)blockIdx.x * 4096 + f * 512 + (k >> 3) * 128 + lm * 8 + (k & 7)] =
                __float2bfloat16(h);
            s1[r] += h * A1;
            s2[r] += h * A2;
        }
    }
#pragma unroll
    for (int r = 0; r < 4; r++) {
        for (int m = 1; m < 16; m <<= 1) {
            s1[r] += __shfl_xor(s1[r], m, 64);
            s2[r] += __shfl_xor(s2[r], m, 64);
        }
    }
    if (lm == 0) {
#pragma unroll
        for (int r = 0; r < 4; r++) {
            int row = r0 + lq * 4 + r;
            atomicAdd(&s1s[row], s1[r]);
            atomicAdd(&s2s[row], s2[r]);
        }
    }
    __syncthreads();
    if (tid < 32) {
        s_src[i0 + tid] = s1s[tid] * LOG2E;
        s_dst[i0 + tid] = s2s[tid] * LOG2E;
    }
}

// ---------------- kernel 2: adj -> 1-bit mask, lane-permuted layout ----------------
template <int NJT>
__global__ void build_mask(const int* __restrict__ adj, unsigned char* __restrict__ mask) {
    size_t gid = (size_t)blockIdx.x * blockDim.x + threadIdx.x;
    const int4* a = (const int4*)(adj + gid * 8);
    int4 v0 = a[0], v1 = a[1];
    unsigned int b = 0;
    b |= (v0.x != 0) ? 1u : 0u;
    b |= (v0.y != 0) ? 2u : 0u;
    b |= (v0.z != 0) ? 4u : 0u;
    b |= (v0.w != 0) ? 8u : 0u;
    b |= (v1.x != 0) ? 16u : 0u;
    b |= (v1.y != 0) ? 32u : 0u;
    b |= (v1.z != 0) ? 64u : 0u;
    b |= (v1.w != 0) ? 128u : 0u;
    unsigned int g = (unsigned int)gid & (NJT * 4 - 1);
    size_t pos = (gid & ~(size_t)(NJT * 4 - 1)) | ((g & 3) * NJT + (g >> 2));
    mask[pos] = (unsigned char)b;
}

__device__ inline short8 make_pfrag(unsigned int cm, float ssi, float4 cd0, float4 cd1,
                                    floatx4* accd, const short8 ones) {
    float p[8];
    float e;
    e = ssi + cd0.x; e = fmaxf(e, 0.01f * e); p[0] = (cm & 1u)   ? __builtin_amdgcn_exp2f(e) : 0.f;
    e = ssi + cd0.y; e = fmaxf(e, 0.01f * e); p[1] = (cm & 2u)   ? __builtin_amdgcn_exp2f(e) : 0.f;
    e = ssi + cd0.z; e = fmaxf(e, 0.01f * e); p[2] = (cm & 4u)   ? __builtin_amdgcn_exp2f(e) : 0.f;
    e = ssi + cd0.w; e = fmaxf(e, 0.01f * e); p[3] = (cm & 8u)   ? __builtin_amdgcn_exp2f(e) : 0.f;
    e = ssi + cd1.x; e = fmaxf(e, 0.01f * e); p[4] = (cm & 16u)  ? __builtin_amdgcn_exp2f(e) : 0.f;
    e = ssi + cd1.y; e = fmaxf(e, 0.01f * e); p[5] = (cm & 32u)  ? __builtin_amdgcn_exp2f(e) : 0.f;
    e = ssi + cd1.z; e = fmaxf(e, 0.01f * e); p[6] = (cm & 64u)  ? __builtin_amdgcn_exp2f(e) : 0.f;
    e = ssi + cd1.w; e = fmaxf(e, 0.01f * e); p[7] = (cm & 128u) ? __builtin_amdgcn_exp2f(e) : 0.f;
    union { short8 v; __hip_bfloat162 q[4]; } af;
    af.q[0] = __float22bfloat162_rn(make_float2(p[0], p[1]));
    af.q[1] = __float22bfloat162_rn(make_float2(p[2], p[3]));
    af.q[2] = __float22bfloat162_rn(make_float2(p[4], p[5]));
    af.q[3] = __float22bfloat162_rn(make_float2(p[6], p[7]));
    *accd = __builtin_amdgcn_mfma_f32_16x16x32_bf16(af.v, ones, *accd, 0, 0, 0);
    return af.v;
}

__device__ inline void keep_frag(short8 v) {
    uint4 u = *(const uint4*)&v;
    asm volatile("" :: "v"(u.x), "v"(u.y), "v"(u.z), "v"(u.w));
}

// ---------------- kernel 3: masked softmax-weighted GEMM (R16) ----------------
template <int NJT>
__global__ __launch_bounds__(256, 2) void gat_attn(
    const unsigned char* __restrict__ mask, const float* __restrict__ s_src,
    const float* __restrict__ s_dst, const float* __restrict__ ba_p,
    const __hip_bfloat16* __restrict__ hbB,
    float* __restrict__ num, float* __restrict__ lpart) {
    int tid = threadIdx.x;
    int w = tid >> 6, lane = tid & 63;
    int lm = lane & 15, lq = lane >> 4;
    int b = blockIdx.x;
    int ib = b & 31;
    int jh = b >> 5;
    int i0 = ib * 256 + w * 64;
    int jb0 = jh * (NJT * 32);

    __shared__ short8 bbuf[3][512];
    __shared__ float sdl[NJT * 32];

    union Mr { uint4 v[NJT / 16]; unsigned int u[NJT / 4]; };
    Mr mr[4];
    const unsigned char* mrow = mask + (size_t)(i0 + lm) * (NN / 8) + jh * (NJT * 4) + lq * NJT;
#pragma unroll
    for (int rg = 0; rg < 4; rg++)
#pragma unroll
        for (int q = 0; q < NJT / 16; q++)
            mr[rg].v[q] = ((const uint4*)(mrow + (size_t)rg * 16 * (NN / 8)))[q];

    float ba = ba_p[0] * LOG2E;
    float ssi[4];
#pragma unroll
    for (int rg = 0; rg < 4; rg++) ssi[rg] = s_src[i0 + rg * 16 + lm] + ba;

    const char* hb0 = (const char*)hbB + (size_t)jh * NJT * 8192;

#define STAGE(tt, p)                                                                 \
    do {                                                                             \
        const char* g_ = hb0 + (size_t)(tt) * 8192 + tid * 16;                       \
        char* l_ = (char*)&bbuf[p][0] + tid * 16;                                    \
        __builtin_amdgcn_global_load_lds(                                            \
            (const __attribute__((address_space(1))) unsigned int*)g_,               \
            (__attribute__((address_space(3))) unsigned int*)l_, 16, 0, 0);          \
        __builtin_amdgcn_global_load_lds(                                            \
            (const __attribute__((address_space(1))) unsigned int*)(g_ + 4096),      \
            (__attribute__((address_space(3))) unsigned int*)(l_ + 4096), 16, 0, 0); \
    } while (0)

    STAGE(0, 0);
    const float* sdg = s_dst + jb0;
    for (int k = tid; k < NJT * 32; k += 256) sdl[k] = sdg[k];
    __syncthreads();

    floatx4 acc[4][8] = {};
    floatx4 accd[4] = {};
    const short8 ones = { 0x3F80, 0x3F80, 0x3F80, 0x3F80, 0x3F80, 0x3F80, 0x3F80, 0x3F80 };

#pragma unroll
    for (int t = 0; t < NJT; t++) {
        if (t + 1 < NJT) {
            STAGE(t + 1, (t + 1) % 3);
            asm volatile("s_waitcnt vmcnt(2)" ::: "memory");
        } else {
            asm volatile("s_waitcnt vmcnt(0)" ::: "memory");
        }
        __builtin_amdgcn_s_barrier();
        __builtin_amdgcn_sched_barrier(0);

        float4 cd0 = *(const float4*)&sdl[t * 32 + lq * 8];
        float4 cd1 = *(const float4*)&sdl[t * 32 + lq * 8 + 4];
        short8 af[4];
#pragma unroll
        for (int rg = 0; rg < 4; rg++) {
            unsigned int cm = (mr[rg].u[t >> 2] >> ((t & 3) * 8)) & 0xFFu;
            af[rg] = make_pfrag(cm, ssi[rg], cd0, cd1, &accd[rg], ones);
        }
#pragma unroll
        for (int f = 0; f < 8; f++) {
            short8 bf = bbuf[t % 3][f * 64 + lane];
#pragma unroll
            for (int rg = 0; rg < 4; rg++)
                acc[rg][f] = __builtin_amdgcn_mfma_f32_16x16x32_bf16(af[rg], bf, acc[rg][f], 0, 0, 0);
        }
    }
#undef STAGE

    float* nb = num + ((size_t)jh * NN + i0) * DOUT;
#pragma unroll
    for (int rg = 0; rg < 4; rg++)
#pragma unroll
        for (int f = 0; f < 8; f++)
#pragma unroll
            for (int r = 0; r < 4; r++)
                nb[(size_t)(rg * 16 + lq * 4 + r) * DOUT + f * 16 + lm] = acc[rg][f][r];
    if (lm == 0) {
#pragma unroll
        for (int rg = 0; rg < 4; rg++)
#pragma unroll
            for (int r = 0; r < 4; r++)
                lpart[(size_t)jh * NN + i0 + rg * 16 + lq * 4 + r] = accd[rg][r];
    }
}

// ---------------- PROBE: R16 attn body, REPS repeats, MODE-ablated ----------------
// MODE 0 full; MODE 1 softmax stubbed (af=ones, loads kept live);
// MODE 2 B-read+MFMA stubbed (af kept live). Writes to scratch.
template <int NJT, int MODE, int REPS>
__global__ __launch_bounds__(256, 2) void gat_attn_probe(
    const unsigned char* __restrict__ mask, const float* __restrict__ s_src,
    const float* __restrict__ s_dst, const float* __restrict__ ba_p,
    const __hip_bfloat16* __restrict__ hbB,
    float* __restrict__ num, float* __restrict__ lpart) {
    int tid = threadIdx.x;
    int w = tid >> 6, lane = tid & 63;
    int lm = lane & 15, lq = lane >> 4;
    int b = blockIdx.x;
    int ib = b & 31;
    int jh = b >> 5;
    int i0 = ib * 256 + w * 64;
    int jb0 = jh * (NJT * 32);

    __shared__ short8 bbuf[3][512];
    __shared__ float sdl[NJT * 32];

    union Mr { uint4 v[NJT / 16]; unsigned int u[NJT / 4]; };
    Mr mr[4];
    const unsigned char* mrow = mask + (size_t)(i0 + lm) * (NN / 8) + jh * (NJT * 4) + lq * NJT;
#pragma unroll
    for (int rg = 0; rg < 4; rg++)
#pragma unroll
        for (int q = 0; q < NJT / 16; q++)
            mr[rg].v[q] = ((const uint4*)(mrow + (size_t)rg * 16 * (NN / 8)))[q];

    float ba = ba_p[0] * LOG2E;
    float ssi[4];
#pragma unroll
    for (int rg = 0; rg < 4; rg++) ssi[rg] = s_src[i0 + rg * 16 + lm] + ba;

    const char* hb0 = (const char*)hbB + (size_t)jh * NJT * 8192;

#define STAGE(tt, p)                                                                 \
    do {                                                                             \
        const char* g_ = hb0 + (size_t)(tt) * 8192 + tid * 16;                       \
        char* l_ = (char*)&bbuf[p][0] + tid * 16;                                    \
        __builtin_amdgcn_global_load_lds(                                            \
            (const __attribute__((address_space(1))) unsigned int*)g_,               \
            (__attribute__((address_space(3))) unsigned int*)l_, 16, 0, 0);          \
        __builtin_amdgcn_global_load_lds(                                            \
            (const __attribute__((address_space(1))) unsigned int*)(g_ + 4096),      \
            (__attribute__((address_space(3))) unsigned int*)(l_ + 4096), 16, 0, 0); \
    } while (0)

    const float* sdg = s_dst + jb0;
    for (int k = tid; k < NJT * 32; k += 256) sdl[k] = sdg[k];
    __syncthreads();

    const short8 ones = { 0x3F80, 0x3F80, 0x3F80, 0x3F80, 0x3F80, 0x3F80, 0x3F80, 0x3F80 };

#pragma unroll 1
    for (int rep = 0; rep < REPS; rep++) {
        STAGE(0, 0);
        floatx4 acc[4][8] = {};
        floatx4 accd[4] = {};
#pragma unroll
        for (int t = 0; t < NJT; t++) {
            if (t + 1 < NJT) {
                STAGE(t + 1, (t + 1) % 3);
                asm volatile("s_waitcnt vmcnt(2)" ::: "memory");
            } else {
                asm volatile("s_waitcnt vmcnt(0)" ::: "memory");
            }
            __builtin_amdgcn_s_barrier();
            __builtin_amdgcn_sched_barrier(0);

            float4 cd0 = *(const float4*)&sdl[t * 32 + lq * 8];
            float4 cd1 = *(const float4*)&sdl[t * 32 + lq * 8 + 4];
            short8 af[4];
            if constexpr (MODE == 1) {
                // softmax stubbed; keep mask-extract + cd + ssi chains live
                unsigned int idum = 0;
                float fdum = cd0.x + cd0.y + cd0.z + cd0.w + cd1.x + cd1.y + cd1.z + cd1.w;
#pragma unroll
                for (int rg = 0; rg < 4; rg++) {
                    idum |= (mr[rg].u[t >> 2] >> ((t & 3) * 8)) & 0xFFu;
                    fdum += ssi[rg];
                    af[rg] = ones;
                }
                asm volatile("" :: "v"(idum), "v"(fdum));
            } else {
#pragma unroll
                for (int rg = 0; rg < 4; rg++) {
                    unsigned int cm = (mr[rg].u[t >> 2] >> ((t & 3) * 8)) & 0xFFu;
                    af[rg] = make_pfrag(cm, ssi[rg], cd0, cd1, &accd[rg], ones);
                }
            }
            if constexpr (MODE == 2) {
                keep_frag(af[0]); keep_frag(af[1]); keep_frag(af[2]); keep_frag(af[3]);
            } else {
#pragma unroll
                for (int f = 0; f < 8; f++) {
                    short8 bf = bbuf[t % 3][f * 64 + lane];
#pragma unroll
                    for (int rg = 0; rg < 4; rg++)
                        acc[rg][f] = __builtin_amdgcn_mfma_f32_16x16x32_bf16(af[rg], bf, acc[rg][f], 0, 0, 0);
                }
            }
        }
        float* nb = num + ((size_t)jh * NN + i0) * DOUT;
#pragma unroll
        for (int rg = 0; rg < 4; rg++)
#pragma unroll
            for (int f = 0; f < 8; f++)
#pragma unroll
                for (int r = 0; r < 4; r++)
                    nb[(size_t)(rg * 16 + lq * 4 + r) * DOUT + f * 16 + lm] = acc[rg][f][r];
        if (lm == 0) {
#pragma unroll
            for (int rg = 0; rg < 4; rg++)
#pragma unroll
                for (int r = 0; r < 4; r++)
                    lpart[(size_t)jh * NN + i0 + rg * 16 + lq * 4 + r] = accd[rg][r];
        }
    }
#undef STAGE
}

// ---------------- kernel 4: combine partials, divide ----------------
__global__ void gat_combine(const float* __restrict__ num, const float* __restrict__ lpart,
                            float* __restrict__ out, int jsplit) {
    int gid = blockIdx.x * blockDim.x + threadIdx.x;
    int idx = gid * 4;
    int i = idx >> 7;
    float den = 0.f;
    for (int s = 0; s < jsplit; s++) den += lpart[(size_t)s * NN + i];
    float inv = 1.0f / den;
    floatx4 o = {0.f, 0.f, 0.f, 0.f};
    for (int s = 0; s < jsplit; s++) {
        floatx4 n = *(const floatx4*)&num[(size_t)s * NN * DOUT + idx];
        o += n;
    }
    o *= inv;
    *(floatx4*)&out[idx] = o;
}

extern "C" void kernel_launch(void* const* d_in, const int* in_sizes, int n_in,
                              void* d_out, int out_size, void* d_ws, size_t ws_size,
                              hipStream_t stream) {
    const float* x  = (const float*)d_in[0];
    const int* adj  = (const int*)d_in[1];
    const float* W  = (const float*)d_in[2];
    const float* bW = (const float*)d_in[3];
    const float* a1 = (const float*)d_in[4];
    const float* a2 = (const float*)d_in[5];
    const float* ba = (const float*)d_in[6];
    float* out = (float*)d_out;

    char* ws = (char*)d_ws;
    __hip_bfloat16* hbB  = (__hip_bfloat16*)ws;                    // 2 MB
    __hip_bfloat16* WT   = (__hip_bfloat16*)(ws + 2097152);        // 64 KB
    float* s_src         = (float*)(ws + 2162688);                 // 32 KB
    float* s_dst         = (float*)(ws + 2195456);                 // 32 KB
    float* lpart         = (float*)(ws + 2228224);                 // 512 KB
    unsigned char* mask  = (unsigned char*)(ws + 2752512);         // 8 MB
    float* num           = (float*)(ws + 11141120);                // jsplit*4 MB

    int jsplit = (ws_size >= 11141120 + (size_t)16 * NN * DOUT * 4) ? 16 : 8;

    if (jsplit == 16) build_mask<16><<<32768, 256, 0, stream>>>(adj, mask);
    else              build_mask<32><<<32768, 256, 0, stream>>>(adj, mask);
    prep_wt<<<128, 256, 0, stream>>>(W, WT);
    gat_h<<<256, 256, 0, stream>>>(x, WT, bW, a1, a2, hbB, s_src, s_dst);
    if (jsplit == 16)
        gat_attn<16><<<512, 256, 0, stream>>>(mask, s_src, s_dst, ba, hbB, num, lpart);
    else
        gat_attn<32><<<256, 256, 0, stream>>>(mask, s_src, s_dst, ba, hbB, num, lpart);
    gat_combine<<<1024, 256, 0, stream>>>(num, lpart, out, jsplit);

    // ---- probes (scratch at +120 MB; run AFTER real pipeline; outputs unaffected) ----
    if (jsplit == 16 && ws_size >= (size_t)120 * 1048576 + (size_t)70 * 1048576) {
        float* pnum   = (float*)(ws + (size_t)120 * 1048576);          // 64 MB scratch
        float* plpart = (float*)(ws + (size_t)185 * 1048576);          // 512 KB scratch
        gat_attn_probe<16, 0, 8><<<512, 256, 0, stream>>>(mask, s_src, s_dst, ba, hbB, pnum, plpart);
        gat_attn_probe<16, 1, 8><<<512, 256, 0, stream>>>(mask, s_src, s_dst, ba, hbB, pnum, plpart);
        gat_attn_probe<16, 2, 8><<<512, 256, 0, stream>>>(mask, s_src, s_dst, ba, hbB, pnum, plpart);
    }
}

// Round 11
// 425.819 us; speedup vs baseline: 2.6859x; 2.6859x over previous
//
#include <hip/hip_runtime.h>
#include <hip/hip_bf16.h>

// GAT layer, N=8192, DIN=256, DOUT=128.
// h = x@W+bW; e_ij = leaky_relu(s_src[i]+s_dst[j]+ba); p = adj ? exp(e) : 0
// (no max-subtraction: |e| <= ~10 unmasked, fp32-safe). out_i = (sum_j p_ij h_j)/(sum_j p_ij).
//
// R18: probe round (R17) proved the attn t-loop compute is irrelevant --
// stubbing softmax (MODE1) or MFMA+B-reads (MODE2) both changed nothing
// (all modes ~406us/8reps). The cost is the memory STRUCTURE: the 64 MB
// num partial-product write stream thrashes L2 (probe FETCH 375 MB: hbB
// staging re-fetches from HBM that should be L2 hits) and the num round
// trip (64 wr + 64 rd + combine kernel) is pure j-split overhead.
// Fix: j-split by WAVE inside the block, not by block. Each block owns
// 32 rows x ALL j; its 4 waves take j-quarters (64 tiles each) with
// wave-PRIVATE double-buffered LDS B-tiles (barrier-free self-paced
// loop, vmcnt(8), rule-18 sched_barrier after waits). End: 2-barrier
// LDS reduction over the 4 waves' acc/accd partials, divide, write out
// DIRECTLY. num/lpart/gat_combine deleted; writes 64.5->4 MB; staging
// stays L2-resident (no competing stream). Grid 256 = 1 block/CU
// (LDS 96.5 KB), occupancy proven irrelevant (R10/R11).

#define NN 8192
#define DIN 256
#define DOUT 128
#define LOG2E 1.4426950408889634f

typedef __attribute__((ext_vector_type(8))) short short8;   // 8 bf16 = 4 VGPRs (MFMA A/B frag)
typedef __attribute__((ext_vector_type(4))) float floatx4;  // MFMA C/D frag

// ---------------- kernel 0: W [256][128] fp32 -> WT [128][256] bf16 ----------------
__global__ void prep_wt(const float* __restrict__ W, __hip_bfloat16* __restrict__ WT) {
    int e = blockIdx.x * blockDim.x + threadIdx.x;
    if (e < DIN * DOUT) {
        int k = e >> 7;
        int d = e & 127;
        WT[d * DIN + k] = __float2bfloat16(W[e]);
    }
}

// ---------------- kernel 1: h = x@W + bW (MFMA), fused s_src/s_dst; h -> hbB frag-tile layout ----------------
// hbB flat index for h-element (row i, dim d):
//   g=i>>5, k=i&31, f=d>>4, n=d&15 -> g*4096 + f*512 + (k>>3)*128 + n*8 + (k&7)
__global__ __launch_bounds__(256, 4) void gat_h(
    const float* __restrict__ x, const __hip_bfloat16* __restrict__ WT,
    const float* __restrict__ bW, const float* __restrict__ a1, const float* __restrict__ a2,
    __hip_bfloat16* __restrict__ hbB, float* __restrict__ s_src, float* __restrict__ s_dst) {
    int tid = threadIdx.x;
    int w = tid >> 6, lane = tid & 63;
    int lm = lane & 15, lq = lane >> 4;
    int i0 = blockIdx.x * 32;
    int r0 = (w >> 1) * 16;
    int c0 = (w & 1) * 64;

    __shared__ float s1s[32], s2s[32];
    if (tid < 32) { s1s[tid] = 0.f; s2s[tid] = 0.f; }
    __syncthreads();

    floatx4 acc[4] = {};
#pragma unroll
    for (int kk = 0; kk < DIN; kk += 32) {
        const float4* xp = (const float4*)&x[(size_t)(i0 + r0 + lm) * DIN + kk + lq * 8];
        float4 xa = xp[0], xb = xp[1];
        union { short8 v; __hip_bfloat16 h[8]; } af;
        af.h[0] = __float2bfloat16(xa.x); af.h[1] = __float2bfloat16(xa.y);
        af.h[2] = __float2bfloat16(xa.z); af.h[3] = __float2bfloat16(xa.w);
        af.h[4] = __float2bfloat16(xb.x); af.h[5] = __float2bfloat16(xb.y);
        af.h[6] = __float2bfloat16(xb.z); af.h[7] = __float2bfloat16(xb.w);
#pragma unroll
        for (int t = 0; t < 4; t++) {
            int d = c0 + 16 * t + lm;
            short8 bf = *(const short8*)&WT[(size_t)d * DIN + kk + lq * 8];
            acc[t] = __builtin_amdgcn_mfma_f32_16x16x32_bf16(af.v, bf, acc[t], 0, 0, 0);
        }
    }
    float s1[4] = {0.f, 0.f, 0.f, 0.f}, s2[4] = {0.f, 0.f, 0.f, 0.f};
#pragma unroll
    for (int t = 0; t < 4; t++) {
        int d = c0 + 16 * t + lm;
        int f = (c0 >> 4) + t;
        float A1 = a1[d], A2 = a2[d], B = bW[d];
#pragma unroll
        for (int r = 0; r < 4; r++) {
            int k = r0 + lq * 4 + r;
            float h = acc[t][r] + B;
            hbB[(size_t)blockIdx.x * 4096 + f * 512 + (k >> 3) * 128 + lm * 8 + (k & 7)] =
                __float2bfloat16(h);
            s1[r] += h * A1;
            s2[r] += h * A2;
        }
    }
#pragma unroll
    for (int r = 0; r < 4; r++) {
        for (int m = 1; m < 16; m <<= 1) {
            s1[r] += __shfl_xor(s1[r], m, 64);
            s2[r] += __shfl_xor(s2[r], m, 64);
        }
    }
    if (lm == 0) {
#pragma unroll
        for (int r = 0; r < 4; r++) {
            int row = r0 + lq * 4 + r;
            atomicAdd(&s1s[row], s1[r]);
            atomicAdd(&s2s[row], s2[r]);
        }
    }
    __syncthreads();
    if (tid < 32) {
        s_src[i0 + tid] = s1s[tid] * LOG2E;   // pre-scale: exp(e) = exp2(e*log2e)
        s_dst[i0 + tid] = s2s[tid] * LOG2E;
    }
}

// ---------------- kernel 2: adj -> 1-bit mask, lane-permuted layout (NJT=16 groups) ----------------
// Contiguous read of the 268 MB adj stream; within each 64-byte group g,
// byte stored at (g&3)*16 + (g>>2) so gat_attn's per-(rg,tb) uint4 is contiguous.
__global__ void build_mask(const int* __restrict__ adj, unsigned char* __restrict__ mask) {
    size_t gid = (size_t)blockIdx.x * blockDim.x + threadIdx.x;  // 8,388,608 threads
    const int4* a = (const int4*)(adj + gid * 8);
    int4 v0 = a[0], v1 = a[1];
    unsigned int b = 0;
    b |= (v0.x != 0) ? 1u : 0u;
    b |= (v0.y != 0) ? 2u : 0u;
    b |= (v0.z != 0) ? 4u : 0u;
    b |= (v0.w != 0) ? 8u : 0u;
    b |= (v1.x != 0) ? 16u : 0u;
    b |= (v1.y != 0) ? 32u : 0u;
    b |= (v1.z != 0) ? 64u : 0u;
    b |= (v1.w != 0) ? 128u : 0u;
    unsigned int g = (unsigned int)gid & 63u;
    size_t pos = (gid & ~(size_t)63) | ((g & 3) * 16 + (g >> 2));
    mask[pos] = (unsigned char)b;
}

__device__ inline short8 make_pfrag(unsigned int cm, float ssi, float4 cd0, float4 cd1,
                                    floatx4* accd, const short8 ones) {
    float p[8];
    float e;
    e = ssi + cd0.x; e = fmaxf(e, 0.01f * e); p[0] = (cm & 1u)   ? __builtin_amdgcn_exp2f(e) : 0.f;
    e = ssi + cd0.y; e = fmaxf(e, 0.01f * e); p[1] = (cm & 2u)   ? __builtin_amdgcn_exp2f(e) : 0.f;
    e = ssi + cd0.z; e = fmaxf(e, 0.01f * e); p[2] = (cm & 4u)   ? __builtin_amdgcn_exp2f(e) : 0.f;
    e = ssi + cd0.w; e = fmaxf(e, 0.01f * e); p[3] = (cm & 8u)   ? __builtin_amdgcn_exp2f(e) : 0.f;
    e = ssi + cd1.x; e = fmaxf(e, 0.01f * e); p[4] = (cm & 16u)  ? __builtin_amdgcn_exp2f(e) : 0.f;
    e = ssi + cd1.y; e = fmaxf(e, 0.01f * e); p[5] = (cm & 32u)  ? __builtin_amdgcn_exp2f(e) : 0.f;
    e = ssi + cd1.z; e = fmaxf(e, 0.01f * e); p[6] = (cm & 64u)  ? __builtin_amdgcn_exp2f(e) : 0.f;
    e = ssi + cd1.w; e = fmaxf(e, 0.01f * e); p[7] = (cm & 128u) ? __builtin_amdgcn_exp2f(e) : 0.f;
    union { short8 v; __hip_bfloat162 q[4]; } af;
    af.q[0] = __float22bfloat162_rn(make_float2(p[0], p[1]));
    af.q[1] = __float22bfloat162_rn(make_float2(p[2], p[3]));
    af.q[2] = __float22bfloat162_rn(make_float2(p[4], p[5]));
    af.q[3] = __float22bfloat162_rn(make_float2(p[6], p[7]));
    *accd = __builtin_amdgcn_mfma_f32_16x16x32_bf16(af.v, ones, *accd, 0, 0, 0);
    return af.v;
}

// ---------------- kernel 3: masked softmax-weighted GEMM, j-split by WAVE, direct out ----------------
// grid = 256 blocks (1/CU), 32 rows each. Wave w handles j in [w*2048,(w+1)*2048)
// as 64 tiles of 32 j; rows as 2 A-frag row-groups. Wave-private LDS double
// buffer (no barriers in main loop). End: LDS reduction across waves -> out.
__global__ __launch_bounds__(256, 1) void gat_attn(
    const unsigned char* __restrict__ mask, const float* __restrict__ s_src,
    const float* __restrict__ s_dst, const float* __restrict__ ba_p,
    const __hip_bfloat16* __restrict__ hbB, float* __restrict__ out) {
    int tid = threadIdx.x;
    int w = tid >> 6, lane = tid & 63;
    int lm = lane & 15, lq = lane >> 4;
    int i0 = blockIdx.x * 32;

    __shared__ short8 bbuf[4][2][512];   // 64 KB: per-wave double-buffered 8 KB B-tiles
    __shared__ float sdl[NN];            // 32 KB: full s_dst
    __shared__ float denr[4][32];        // 512 B: per-wave denominators

    // masks: mr[rg][tb] = uint4 covering 16 tiles (tb = t>>4) for row i0+rg*16+lm.
    // permuted layout: byte (row, w, tb, lq, ti) at row*1024 + (w*4+tb)*64 + lq*16 + ti.
    uint4 mr[2][4];
#pragma unroll
    for (int rg = 0; rg < 2; rg++)
#pragma unroll
        for (int tb = 0; tb < 4; tb++)
            mr[rg][tb] = *(const uint4*)(mask + (size_t)(i0 + rg * 16 + lm) * (NN / 8)
                                              + (w * 4 + tb) * 64 + lq * 16);

    float ba = ba_p[0] * LOG2E;
    float ssi0 = s_src[i0 + lm] + ba;
    float ssi1 = s_src[i0 + 16 + lm] + ba;

    for (int k = tid; k < NN; k += 256) sdl[k] = s_dst[k];

    const char* hbc = (const char*)hbB + (size_t)w * 64 * 8192;   // wave's j-quarter

#define STAGEW(T, par)                                                                  \
    do {                                                                                \
        const char* g_ = hbc + (size_t)(T) * 8192 + lane * 16;                          \
        char* l_ = (char*)&bbuf[w][par][0] + lane * 16;                                 \
        _Pragma("unroll")                                                               \
        for (int q_ = 0; q_ < 8; q_++)                                                  \
            __builtin_amdgcn_global_load_lds(                                           \
                (const __attribute__((address_space(1))) unsigned int*)(g_ + q_ * 1024),\
                (__attribute__((address_space(3))) unsigned int*)(l_ + q_ * 1024),      \
                16, 0, 0);                                                              \
    } while (0)

    STAGEW(0, 0);
    __syncthreads();   // sdl ready; also drains tile 0 (fine, prologue only)

    floatx4 acc[2][8] = {};
    floatx4 accd[2] = {};
    const short8 ones = { 0x3F80, 0x3F80, 0x3F80, 0x3F80, 0x3F80, 0x3F80, 0x3F80, 0x3F80 };

#pragma unroll
    for (int tb = 0; tb < 4; tb++) {
#pragma unroll
        for (int ti = 0; ti < 16; ti++) {
            const int t = tb * 16 + ti;
            if (t < 63) {
                STAGEW(t + 1, (t + 1) & 1);
                asm volatile("s_waitcnt vmcnt(8)" ::: "memory");  // tile t landed; t+1 in flight
            } else {
                asm volatile("s_waitcnt vmcnt(0)" ::: "memory");
            }
            __builtin_amdgcn_sched_barrier(0);

            float4 cd0 = *(const float4*)&sdl[w * 2048 + t * 32 + lq * 8];
            float4 cd1 = *(const float4*)&sdl[w * 2048 + t * 32 + lq * 8 + 4];
            unsigned int u0 = ((const unsigned int*)&mr[0][tb])[ti >> 2];
            unsigned int u1 = ((const unsigned int*)&mr[1][tb])[ti >> 2];
            unsigned int cm0 = (u0 >> ((ti & 3) * 8)) & 0xFFu;
            unsigned int cm1 = (u1 >> ((ti & 3) * 8)) & 0xFFu;
            short8 af0 = make_pfrag(cm0, ssi0, cd0, cd1, &accd[0], ones);
            short8 af1 = make_pfrag(cm1, ssi1, cd0, cd1, &accd[1], ones);
#pragma unroll
            for (int f = 0; f < 8; f++) {
                short8 bf = bbuf[w][t & 1][f * 64 + lane];
                acc[0][f] = __builtin_amdgcn_mfma_f32_16x16x32_bf16(af0, bf, acc[0][f], 0, 0, 0);
                acc[1][f] = __builtin_amdgcn_mfma_f32_16x16x32_bf16(af1, bf, acc[1][f], 0, 0, 0);
            }
        }
    }
#undef STAGEW

    // ---- cross-wave reduction (reuse bbuf as red[4][32][128]) ----
    __syncthreads();   // all waves done with their bbuf reads
    float* red = (float*)bbuf;
#pragma unroll
    for (int rg = 0; rg < 2; rg++)
#pragma unroll
        for (int f = 0; f < 8; f++)
#pragma unroll
            for (int r = 0; r < 4; r++)
                red[w * 4096 + (rg * 16 + lq * 4 + r) * 128 + f * 16 + lm] = acc[rg][f][r];
    if (lm == 0) {
#pragma unroll
        for (int rg = 0; rg < 2; rg++)
#pragma unroll
            for (int r = 0; r < 4; r++)
                denr[w][rg * 16 + lq * 4 + r] = accd[rg][r];
    }
    __syncthreads();

    // each thread: one row-octet slice (16 dims), coalesced out write
    int row = tid >> 3;
    int d0 = (tid & 7) * 16;
    float den = denr[0][row] + denr[1][row] + denr[2][row] + denr[3][row];
    float inv = 1.0f / den;
    float* ob = out + (size_t)(i0 + row) * DOUT + d0;
#pragma unroll
    for (int c = 0; c < 4; c++) {
        int idx = row * 128 + d0 + c * 4;
        floatx4 s = *(const floatx4*)&red[idx];
        s += *(const floatx4*)&red[4096 + idx];
        s += *(const floatx4*)&red[8192 + idx];
        s += *(const floatx4*)&red[12288 + idx];
        s *= inv;
        *(floatx4*)(ob + c * 4) = s;
    }
}

extern "C" void kernel_launch(void* const* d_in, const int* in_sizes, int n_in,
                              void* d_out, int out_size, void* d_ws, size_t ws_size,
                              hipStream_t stream) {
    const float* x  = (const float*)d_in[0];
    const int* adj  = (const int*)d_in[1];
    const float* W  = (const float*)d_in[2];
    const float* bW = (const float*)d_in[3];
    const float* a1 = (const float*)d_in[4];
    const float* a2 = (const float*)d_in[5];
    const float* ba = (const float*)d_in[6];
    float* out = (float*)d_out;

    char* ws = (char*)d_ws;
    __hip_bfloat16* hbB  = (__hip_bfloat16*)ws;                    // 2 MB   frag-tile layout
    __hip_bfloat16* WT   = (__hip_bfloat16*)(ws + 2097152);        // 64 KB
    float* s_src         = (float*)(ws + 2162688);                 // 32 KB (pre-scaled by log2e)
    float* s_dst         = (float*)(ws + 2195456);                 // 32 KB (pre-scaled by log2e)
    unsigned char* mask  = (unsigned char*)(ws + 2752512);         // 8 MB   permuted

    // build_mask first: keeps gat_h's outputs (hbB/s_dst) L2-warm for gat_attn.
    build_mask<<<32768, 256, 0, stream>>>(adj, mask);
    prep_wt<<<128, 256, 0, stream>>>(W, WT);
    gat_h<<<256, 256, 0, stream>>>(x, WT, bW, a1, a2, hbB, s_src, s_dst);
    gat_attn<<<256, 256, 0, stream>>>(mask, s_src, s_dst, ba, hbB, out);
}